// Round 1
// baseline (592.058 us; speedup 1.0000x reference)
//
#include <hip/hip_runtime.h>

#define HW 4096
#define NC 256
#define NB 8
#define GN_EPS 1e-5f

typedef short bf16x8 __attribute__((ext_vector_type(8)));
typedef float f32x4 __attribute__((ext_vector_type(4)));

#define MFMA16 __builtin_amdgcn_mfma_f32_16x16x32_bf16

// XOR swizzle key: distinct 16B-slot for 8 consecutive rows, mixed with row>>3
// so stride-4 / stride-8 writers also spread. Window = 128 B.
#define SWZ(row) ((((row) & 7) ^ (((row) >> 3) & 7)) << 4)

__device__ __forceinline__ unsigned short f2bf(float f) {
  unsigned int u = __float_as_uint(f);
  u = (u + 0x7FFFu + ((u >> 16) & 1u)) >> 16;
  return (unsigned short)u;
}

// ---------------------------------------------------------------- kernel 1
// GroupNorm stats: one block per (b, g). Group = 8 contiguous channels
// = 32768 contiguous floats. Emit per-channel scale s = rstd*w and
// shift t = b - mean*s so GN can be fused into QKV A-staging.
__global__ void gn_stats_kernel(const float* __restrict__ x,
                                const float* __restrict__ gnw,
                                const float* __restrict__ gnb,
                                float* __restrict__ s_arr,
                                float* __restrict__ t_arr) {
  int bg = blockIdx.x;
  int b = bg >> 5, g = bg & 31;
  const float4* base = (const float4*)(x + ((size_t)b * NC + g * 8) * HW);
  int tid = threadIdx.x;
  float s = 0.f, ss = 0.f;
  for (int it = 0; it < 32; ++it) {
    float4 v = base[tid + it * 256];
    s += v.x + v.y + v.z + v.w;
    ss += v.x * v.x + v.y * v.y + v.z * v.z + v.w * v.w;
  }
  for (int off = 32; off; off >>= 1) {
    s += __shfl_down(s, off);
    ss += __shfl_down(ss, off);
  }
  __shared__ float red[8];
  __shared__ float bc[2];
  int wave = tid >> 6, lane = tid & 63;
  if (lane == 0) { red[wave] = s; red[4 + wave] = ss; }
  __syncthreads();
  if (tid == 0) {
    float S = red[0] + red[1] + red[2] + red[3];
    float SS = red[4] + red[5] + red[6] + red[7];
    float mean = S * (1.f / 32768.f);
    float var = SS * (1.f / 32768.f) - mean * mean;
    bc[0] = mean;
    bc[1] = rsqrtf(var + GN_EPS);
  }
  __syncthreads();
  if (tid < 8) {
    int c = g * 8 + tid;
    float sv = bc[1] * gnw[c];
    s_arr[b * NC + c] = sv;
    t_arr[b * NC + c] = gnb[c] - bc[0] * sv;
  }
}

// ---------------------------------------------------------------- kernel 2
// QKV GEMM, C^T orientation: D[p][o] = sum_c xn^T[p][c] * W^T[c][o].
// GN fused into A staging. Writes q,k,v as (b, pix, 256) bf16.
// q rows scaled by 1/sqrt(c)=1/16 (exact in bf16).
__global__ __launch_bounds__(256) void qkv_gemm_kernel(
    const float* __restrict__ x, const float* __restrict__ s_arr,
    const float* __restrict__ t_arr, const float* __restrict__ w,
    const float* __restrict__ bias, unsigned short* __restrict__ qb,
    unsigned short* __restrict__ kb, unsigned short* __restrict__ vb) {
  int b = blockIdx.z;
  int p0 = blockIdx.x * 64;
  int o0 = blockIdx.y * 128;
  int tid = threadIdx.x;
  int wave = tid >> 6, lane = tid & 63;
  int l15 = lane & 15, q4 = lane >> 4;
  int wm = wave >> 1, wn = wave & 1;
  __shared__ unsigned short a_lds[64 * 64];   // [p][c] swizzled
  __shared__ unsigned short b_lds[128 * 64];  // [o][c] swizzled
  char* aB = (char*)a_lds;
  char* bB = (char*)b_lds;
  f32x4 acc[2][4];
  for (int i = 0; i < 2; ++i)
    for (int j = 0; j < 4; ++j) acc[i][j] = (f32x4){0.f, 0.f, 0.f, 0.f};

  for (int kc0 = 0; kc0 < 256; kc0 += 64) {
    __syncthreads();
    // stage A: xn^T tile 64p x 64c (transpose via per-element LDS writes)
    for (int it = 0; it < 4; ++it) {
      int idx = tid + it * 256;
      int c = idx >> 4, p4 = idx & 15;
      float4 xv = *(const float4*)(x + ((size_t)b * NC + kc0 + c) * HW + p0 + p4 * 4);
      float sc = s_arr[b * NC + kc0 + c];
      float tc = t_arr[b * NC + kc0 + c];
      float vals[4] = {xv.x, xv.y, xv.z, xv.w};
      for (int i = 0; i < 4; ++i) {
        int p = p4 * 4 + i;
        *(unsigned short*)(aB + ((p * 128 + c * 2) ^ SWZ(p))) =
            f2bf(vals[i] * sc + tc);
      }
    }
    // stage B: W^T tile 128o x 64c (straight copy + bf16 convert)
    for (int it = 0; it < 8; ++it) {
      int idx = tid + it * 256;
      int o = idx >> 4, c4 = idx & 15;
      float4 wv = *(const float4*)(w + (size_t)(o0 + o) * NC + kc0 + c4 * 4);
      ushort4 hv = make_ushort4(f2bf(wv.x), f2bf(wv.y), f2bf(wv.z), f2bf(wv.w));
      *(ushort4*)(bB + ((o * 128 + c4 * 8) ^ SWZ(o))) = hv;
    }
    __syncthreads();
    for (int kk = 0; kk < 2; ++kk) {
      bf16x8 af[2], bfv[4];
      for (int pb = 0; pb < 2; ++pb) {
        int row = wm * 32 + pb * 16 + l15;
        af[pb] = *(const bf16x8*)(aB + ((row * 128 + kk * 64 + q4 * 16) ^ SWZ(row)));
      }
      for (int ob = 0; ob < 4; ++ob) {
        int row = wn * 64 + ob * 16 + l15;
        bfv[ob] = *(const bf16x8*)(bB + ((row * 128 + kk * 64 + q4 * 16) ^ SWZ(row)));
      }
      for (int pb = 0; pb < 2; ++pb)
        for (int ob = 0; ob < 4; ++ob)
          acc[pb][ob] = MFMA16(af[pb], bfv[ob], acc[pb][ob], 0, 0, 0);
    }
  }
  for (int pb = 0; pb < 2; ++pb) {
    for (int ob = 0; ob < 4; ++ob) {
      int og = o0 + wn * 64 + ob * 16 + l15;
      int tsel = og >> 8, oc = og & 255;
      unsigned short* dst = tsel == 0 ? qb : (tsel == 1 ? kb : vb);
      float bi = bias[og];
      float qscale = (tsel == 0) ? 0.0625f : 1.0f;
      for (int r = 0; r < 4; ++r) {
        int p = p0 + wm * 32 + pb * 16 + q4 * 4 + r;
        dst[((size_t)b * HW + p) * NC + oc] = f2bf((acc[pb][ob][r] + bi) * qscale);
      }
    }
  }
}

// ---------------------------------------------------------------- kernel 3
// v (b, pix, c) -> vT (b, c, pix), 64x64 LDS tiles, swizzled.
__global__ void transpose_v_kernel(const unsigned short* __restrict__ vb,
                                   unsigned short* __restrict__ vT) {
  int b = blockIdx.z;
  int p0 = blockIdx.x * 64, c0 = blockIdx.y * 64;
  int tid = threadIdx.x;
  __shared__ unsigned short tl[64 * 64];  // [c][p] swizzled
  char* tB = (char*)tl;
  for (int rep = 0; rep < 2; ++rep) {
    int p = (tid >> 3) + rep * 32;
    int c8 = (tid & 7) * 8;
    uint4 raw = *(const uint4*)(vb + ((size_t)b * HW + p0 + p) * NC + c0 + c8);
    unsigned int rr[4] = {raw.x, raw.y, raw.z, raw.w};
    for (int i = 0; i < 4; ++i) {
      int c_a = c8 + i * 2, c_b = c8 + i * 2 + 1;
      *(unsigned short*)(tB + ((c_a * 128 + p * 2) ^ SWZ(c_a))) =
          (unsigned short)(rr[i] & 0xffffu);
      *(unsigned short*)(tB + ((c_b * 128 + p * 2) ^ SWZ(c_b))) =
          (unsigned short)(rr[i] >> 16);
    }
  }
  __syncthreads();
  for (int rep = 0; rep < 2; ++rep) {
    int c = (tid >> 3) + rep * 32;
    int p8 = (tid & 7) * 8;
    bf16x8 val = *(const bf16x8*)(tB + ((c * 128 + p8 * 2) ^ SWZ(c)));
    *(bf16x8*)(vT + ((size_t)b * NC + c0 + c) * HW + p0 + p8) = val;
  }
}

// ---------------------------------------------------------------- kernel 4
// Flash attention. Block = (batch, 64 q rows), 4 waves x 16 rows.
// Q in registers; K tile (64x256) and V^T tile (256x64) staged in
// swizzled LDS each KV step; online softmax in registers; P routed via
// per-wave LDS to become the PV A-operand.
__global__ __launch_bounds__(256, 2) void flash_attn_kernel(
    const unsigned short* __restrict__ qb, const unsigned short* __restrict__ kb,
    const unsigned short* __restrict__ vT, unsigned short* __restrict__ att) {
  int b = blockIdx.y;
  int qt = blockIdx.x;
  int tid = threadIdx.x;
  int wave = tid >> 6, lane = tid & 63;
  int l15 = lane & 15, q4 = lane >> 4;
  __shared__ unsigned short k_lds[64 * 256];  // [j][c] swizzled (512B rows)
  __shared__ unsigned short v_lds[256 * 64];  // [c][j] swizzled (128B rows)
  __shared__ unsigned short p_lds[4][16 * 64];
  char* kB = (char*)k_lds;
  char* vB = (char*)v_lds;
  char* pB = (char*)p_lds[wave];

  bf16x8 qf[8];
  const unsigned short* qrow =
      qb + ((size_t)b * HW + qt * 64 + wave * 16 + l15) * NC;
  for (int kc = 0; kc < 8; ++kc)
    qf[kc] = *(const bf16x8*)(qrow + kc * 32 + q4 * 8);

  f32x4 acc[16];
  for (int i = 0; i < 16; ++i) acc[i] = (f32x4){0.f, 0.f, 0.f, 0.f};
  float m_r[4] = {-1e30f, -1e30f, -1e30f, -1e30f};
  float l_r[4] = {0.f, 0.f, 0.f, 0.f};

  for (int j0 = 0; j0 < HW; j0 += 64) {
    __syncthreads();
    for (int it = 0; it < 8; ++it) {  // stage K
      int idx = tid + it * 256;
      int j = idx >> 5, c16 = idx & 31;
      uint4 raw = *(const uint4*)(kb + ((size_t)b * HW + j0 + j) * NC + c16 * 8);
      *(uint4*)(kB + ((j * 512 + c16 * 16) ^ SWZ(j))) = raw;
    }
    for (int it = 0; it < 8; ++it) {  // stage V^T
      int idx = tid + it * 256;
      int cc = idx >> 3, j8 = idx & 7;
      uint4 raw = *(const uint4*)(vT + ((size_t)b * NC + cc) * HW + j0 + j8 * 8);
      *(uint4*)(vB + ((cc * 128 + j8 * 16) ^ SWZ(cc))) = raw;
    }
    __syncthreads();

    // S = Q K^T  (rows: q4*4+r, cols: jb*16+l15)
    f32x4 sv[4];
    for (int jb = 0; jb < 4; ++jb) {
      f32x4 a = (f32x4){0.f, 0.f, 0.f, 0.f};
      int j = jb * 16 + l15;
      for (int kc = 0; kc < 8; ++kc) {
        bf16x8 kf = *(const bf16x8*)(kB + ((j * 512 + kc * 64 + q4 * 16) ^ SWZ(j)));
        a = MFMA16(qf[kc], kf, a, 0, 0, 0);
      }
      sv[jb] = a;
    }

    // online softmax (reduce across the 16 lanes sharing rows)
    float sf[4];
    for (int r = 0; r < 4; ++r) {
      float mx = fmaxf(fmaxf(sv[0][r], sv[1][r]), fmaxf(sv[2][r], sv[3][r]));
      mx = fmaxf(mx, __shfl_xor(mx, 1));
      mx = fmaxf(mx, __shfl_xor(mx, 2));
      mx = fmaxf(mx, __shfl_xor(mx, 4));
      mx = fmaxf(mx, __shfl_xor(mx, 8));
      float mn = fmaxf(m_r[r], mx);
      float f = __expf(m_r[r] - mn);
      float rs = 0.f;
      for (int jb = 0; jb < 4; ++jb) {
        float p = __expf(sv[jb][r] - mn);
        sv[jb][r] = p;
        rs += p;
      }
      rs += __shfl_xor(rs, 1);
      rs += __shfl_xor(rs, 2);
      rs += __shfl_xor(rs, 4);
      rs += __shfl_xor(rs, 8);
      l_r[r] = l_r[r] * f + rs;
      m_r[r] = mn;
      sf[r] = f;
    }
    for (int nb = 0; nb < 16; ++nb) {
      f32x4 t = acc[nb];
      t[0] *= sf[0]; t[1] *= sf[1]; t[2] *= sf[2]; t[3] *= sf[3];
      acc[nb] = t;
    }

    // P -> per-wave LDS (bf16), then read back as PV A-fragments
    for (int jb = 0; jb < 4; ++jb)
      for (int r = 0; r < 4; ++r) {
        int row = q4 * 4 + r;
        *(unsigned short*)(pB + ((row * 128 + (jb * 16 + l15) * 2) ^ SWZ(row))) =
            f2bf(sv[jb][r]);
      }
    bf16x8 pa[2];
    for (int kj = 0; kj < 2; ++kj)
      pa[kj] = *(const bf16x8*)(pB + ((l15 * 128 + kj * 64 + q4 * 16) ^ SWZ(l15)));

    for (int nb = 0; nb < 16; ++nb) {
      int cc = nb * 16 + l15;
      for (int kj = 0; kj < 2; ++kj) {
        bf16x8 vf = *(const bf16x8*)(vB + ((cc * 128 + kj * 64 + q4 * 16) ^ SWZ(cc)));
        acc[nb] = MFMA16(pa[kj], vf, acc[nb], 0, 0, 0);
      }
    }
  }

  float inv[4];
  for (int r = 0; r < 4; ++r) inv[r] = 1.f / l_r[r];
  for (int nb = 0; nb < 16; ++nb)
    for (int r = 0; r < 4; ++r) {
      int p = qt * 64 + wave * 16 + q4 * 4 + r;
      att[((size_t)b * HW + p) * NC + nb * 16 + l15] = f2bf(acc[nb][r] * inv[r]);
    }
}

// ---------------------------------------------------------------- kernel 5
// out = out_w @ att^T + out_b + x.  C orientation: D[o][p], fp32 stores
// coalesced (lanes = consecutive p).
__global__ __launch_bounds__(256) void outproj_kernel(
    const float* __restrict__ ow, const float* __restrict__ obias,
    const unsigned short* __restrict__ att, const float* __restrict__ x,
    float* __restrict__ out) {
  int b = blockIdx.y;
  int p0 = blockIdx.x * 64;
  int tid = threadIdx.x;
  int wave = tid >> 6, lane = tid & 63;
  int l15 = lane & 15, q4 = lane >> 4;
  __shared__ unsigned short aw_lds[256 * 64];  // [o][c] swizzled
  __shared__ unsigned short bt_lds[64 * 64];   // [p][c] swizzled
  char* aB = (char*)aw_lds;
  char* bB = (char*)bt_lds;
  f32x4 acc[4][4];
  for (int i = 0; i < 4; ++i)
    for (int j = 0; j < 4; ++j) acc[i][j] = (f32x4){0.f, 0.f, 0.f, 0.f};

  for (int kc0 = 0; kc0 < 256; kc0 += 64) {
    __syncthreads();
    for (int it = 0; it < 16; ++it) {  // stage out_w tile
      int idx = tid + it * 256;
      int o = idx >> 4, c4 = idx & 15;
      float4 wv = *(const float4*)(ow + (size_t)o * NC + kc0 + c4 * 4);
      ushort4 hv = make_ushort4(f2bf(wv.x), f2bf(wv.y), f2bf(wv.z), f2bf(wv.w));
      *(ushort4*)(aB + ((o * 128 + c4 * 8) ^ SWZ(o))) = hv;
    }
    for (int it = 0; it < 2; ++it) {  // stage att tile
      int idx = tid + it * 256;
      int p = idx >> 3, c8 = idx & 7;
      uint4 raw = *(const uint4*)(att + ((size_t)b * HW + p0 + p) * NC + kc0 + c8 * 8);
      *(uint4*)(bB + ((p * 128 + c8 * 16) ^ SWZ(p))) = raw;
    }
    __syncthreads();
    for (int kk = 0; kk < 2; ++kk) {
      bf16x8 af[4], bfv[4];
      for (int obk = 0; obk < 4; ++obk) {
        int row = wave * 64 + obk * 16 + l15;
        af[obk] = *(const bf16x8*)(aB + ((row * 128 + kk * 64 + q4 * 16) ^ SWZ(row)));
      }
      for (int pb = 0; pb < 4; ++pb) {
        int row = pb * 16 + l15;
        bfv[pb] = *(const bf16x8*)(bB + ((row * 128 + kk * 64 + q4 * 16) ^ SWZ(row)));
      }
      for (int obk = 0; obk < 4; ++obk)
        for (int pb = 0; pb < 4; ++pb)
          acc[obk][pb] = MFMA16(af[obk], bfv[pb], acc[obk][pb], 0, 0, 0);
    }
  }
  for (int obk = 0; obk < 4; ++obk)
    for (int pb = 0; pb < 4; ++pb)
      for (int r = 0; r < 4; ++r) {
        int o = wave * 64 + obk * 16 + q4 * 4 + r;
        int p = p0 + pb * 16 + l15;
        size_t gi = ((size_t)b * NC + o) * HW + p;
        out[gi] = acc[obk][pb][r] + obias[o] + x[gi];
      }
}

// ---------------------------------------------------------------- launch
extern "C" void kernel_launch(void* const* d_in, const int* in_sizes, int n_in,
                              void* d_out, int out_size, void* d_ws, size_t ws_size,
                              hipStream_t stream) {
  (void)in_sizes; (void)n_in; (void)out_size; (void)ws_size;
  const float* x = (const float*)d_in[0];
  const float* gnw = (const float*)d_in[1];
  const float* gnb = (const float*)d_in[2];
  const float* qkvw = (const float*)d_in[3];
  const float* qkvb = (const float*)d_in[4];
  const float* ow = (const float*)d_in[5];
  const float* obias = (const float*)d_in[6];
  float* out = (float*)d_out;

  char* ws = (char*)d_ws;
  float* s_arr = (float*)ws;                       // 8*256 f32
  float* t_arr = s_arr + NB * NC;                  // 8*256 f32
  unsigned short* qb = (unsigned short*)(ws + 16384);
  size_t tsz = (size_t)NB * HW * NC;               // 8M bf16 = 16 MB each
  unsigned short* kb = qb + tsz;
  unsigned short* vb = kb + tsz;
  unsigned short* vT = vb + tsz;
  unsigned short* att = vT + tsz;

  hipLaunchKernelGGL(gn_stats_kernel, dim3(NB * 32), dim3(256), 0, stream,
                     x, gnw, gnb, s_arr, t_arr);
  hipLaunchKernelGGL(qkv_gemm_kernel, dim3(64, 6, NB), dim3(256), 0, stream,
                     x, s_arr, t_arr, qkvw, qkvb, qb, kb, vb);
  hipLaunchKernelGGL(transpose_v_kernel, dim3(64, 4, NB), dim3(256), 0, stream,
                     vb, vT);
  hipLaunchKernelGGL(flash_attn_kernel, dim3(64, NB), dim3(256), 0, stream,
                     qb, kb, vT, att);
  hipLaunchKernelGGL(outproj_kernel, dim3(64, NB), dim3(256), 0, stream,
                     ow, obias, att, x, out);
}

// Round 2
// 562.725 us; speedup vs baseline: 1.0521x; 1.0521x over previous
//
#include <hip/hip_runtime.h>

#define HW 4096
#define NC 256
#define NB 8
#define GN_EPS 1e-5f

typedef short bf16x8 __attribute__((ext_vector_type(8)));
typedef float f32x4 __attribute__((ext_vector_type(4)));

#define MFMA16 __builtin_amdgcn_mfma_f32_16x16x32_bf16

// XOR swizzle key: distinct 16B-slot for 8 consecutive rows, mixed with row>>3
// so stride-4 / stride-8 writers also spread. Window = 128 B.
#define SWZ(row) ((((row) & 7) ^ (((row) >> 3) & 7)) << 4)

__device__ __forceinline__ unsigned short f2bf(float f) {
  unsigned int u = __float_as_uint(f);
  u = (u + 0x7FFFu + ((u >> 16) & 1u)) >> 16;
  return (unsigned short)u;
}

// async global->LDS, 16B per lane. LDS dst must be wave-uniform; HW adds lane*16.
__device__ __forceinline__ void gload16(const void* g, void* l) {
  __builtin_amdgcn_global_load_lds(
      (const __attribute__((address_space(1))) void*)g,
      (__attribute__((address_space(3))) void*)l, 16, 0, 0);
}

// ---------------------------------------------------------------- kernel 1
__global__ void gn_stats_kernel(const float* __restrict__ x,
                                const float* __restrict__ gnw,
                                const float* __restrict__ gnb,
                                float* __restrict__ s_arr,
                                float* __restrict__ t_arr) {
  int bg = blockIdx.x;
  int b = bg >> 5, g = bg & 31;
  const float4* base = (const float4*)(x + ((size_t)b * NC + g * 8) * HW);
  int tid = threadIdx.x;
  float s = 0.f, ss = 0.f;
  for (int it = 0; it < 32; ++it) {
    float4 v = base[tid + it * 256];
    s += v.x + v.y + v.z + v.w;
    ss += v.x * v.x + v.y * v.y + v.z * v.z + v.w * v.w;
  }
  for (int off = 32; off; off >>= 1) {
    s += __shfl_down(s, off);
    ss += __shfl_down(ss, off);
  }
  __shared__ float red[8];
  __shared__ float bc[2];
  int wave = tid >> 6, lane = tid & 63;
  if (lane == 0) { red[wave] = s; red[4 + wave] = ss; }
  __syncthreads();
  if (tid == 0) {
    float S = red[0] + red[1] + red[2] + red[3];
    float SS = red[4] + red[5] + red[6] + red[7];
    float mean = S * (1.f / 32768.f);
    float var = SS * (1.f / 32768.f) - mean * mean;
    bc[0] = mean;
    bc[1] = rsqrtf(var + GN_EPS);
  }
  __syncthreads();
  if (tid < 8) {
    int c = g * 8 + tid;
    float sv = bc[1] * gnw[c];
    s_arr[b * NC + c] = sv;
    t_arr[b * NC + c] = gnb[c] - bc[0] * sv;
  }
}

// ---------------------------------------------------------------- kernel 2
__global__ __launch_bounds__(256) void qkv_gemm_kernel(
    const float* __restrict__ x, const float* __restrict__ s_arr,
    const float* __restrict__ t_arr, const float* __restrict__ w,
    const float* __restrict__ bias, unsigned short* __restrict__ qb,
    unsigned short* __restrict__ kb, unsigned short* __restrict__ vb) {
  int b = blockIdx.z;
  int p0 = blockIdx.x * 64;
  int o0 = blockIdx.y * 128;
  int tid = threadIdx.x;
  int wave = tid >> 6, lane = tid & 63;
  int l15 = lane & 15, q4 = lane >> 4;
  int wm = wave >> 1, wn = wave & 1;
  __shared__ unsigned short a_lds[64 * 64];   // [p][c] swizzled
  __shared__ unsigned short b_lds[128 * 64];  // [o][c] swizzled
  char* aB = (char*)a_lds;
  char* bB = (char*)b_lds;
  f32x4 acc[2][4];
  for (int i = 0; i < 2; ++i)
    for (int j = 0; j < 4; ++j) acc[i][j] = (f32x4){0.f, 0.f, 0.f, 0.f};

  for (int kc0 = 0; kc0 < 256; kc0 += 64) {
    __syncthreads();
    for (int it = 0; it < 4; ++it) {
      int idx = tid + it * 256;
      int c = idx >> 4, p4 = idx & 15;
      float4 xv = *(const float4*)(x + ((size_t)b * NC + kc0 + c) * HW + p0 + p4 * 4);
      float sc = s_arr[b * NC + kc0 + c];
      float tc = t_arr[b * NC + kc0 + c];
      float vals[4] = {xv.x, xv.y, xv.z, xv.w};
      for (int i = 0; i < 4; ++i) {
        int p = p4 * 4 + i;
        *(unsigned short*)(aB + ((p * 128 + c * 2) ^ SWZ(p))) =
            f2bf(vals[i] * sc + tc);
      }
    }
    for (int it = 0; it < 8; ++it) {
      int idx = tid + it * 256;
      int o = idx >> 4, c4 = idx & 15;
      float4 wv = *(const float4*)(w + (size_t)(o0 + o) * NC + kc0 + c4 * 4);
      ushort4 hv = make_ushort4(f2bf(wv.x), f2bf(wv.y), f2bf(wv.z), f2bf(wv.w));
      *(ushort4*)(bB + ((o * 128 + c4 * 8) ^ SWZ(o))) = hv;
    }
    __syncthreads();
    for (int kk = 0; kk < 2; ++kk) {
      bf16x8 af[2], bfv[4];
      for (int pb = 0; pb < 2; ++pb) {
        int row = wm * 32 + pb * 16 + l15;
        af[pb] = *(const bf16x8*)(aB + ((row * 128 + kk * 64 + q4 * 16) ^ SWZ(row)));
      }
      for (int ob = 0; ob < 4; ++ob) {
        int row = wn * 64 + ob * 16 + l15;
        bfv[ob] = *(const bf16x8*)(bB + ((row * 128 + kk * 64 + q4 * 16) ^ SWZ(row)));
      }
      for (int pb = 0; pb < 2; ++pb)
        for (int ob = 0; ob < 4; ++ob)
          acc[pb][ob] = MFMA16(af[pb], bfv[ob], acc[pb][ob], 0, 0, 0);
    }
  }
  for (int pb = 0; pb < 2; ++pb) {
    for (int ob = 0; ob < 4; ++ob) {
      int og = o0 + wn * 64 + ob * 16 + l15;
      int tsel = og >> 8, oc = og & 255;
      unsigned short* dst = tsel == 0 ? qb : (tsel == 1 ? kb : vb);
      float bi = bias[og];
      float qscale = (tsel == 0) ? 0.0625f : 1.0f;
      for (int r = 0; r < 4; ++r) {
        int p = p0 + wm * 32 + pb * 16 + q4 * 4 + r;
        dst[((size_t)b * HW + p) * NC + oc] = f2bf((acc[pb][ob][r] + bi) * qscale);
      }
    }
  }
}

// ---------------------------------------------------------------- kernel 3
__global__ void transpose_v_kernel(const unsigned short* __restrict__ vb,
                                   unsigned short* __restrict__ vT) {
  int b = blockIdx.z;
  int p0 = blockIdx.x * 64, c0 = blockIdx.y * 64;
  int tid = threadIdx.x;
  __shared__ unsigned short tl[64 * 64];  // [c][p] swizzled
  char* tB = (char*)tl;
  for (int rep = 0; rep < 2; ++rep) {
    int p = (tid >> 3) + rep * 32;
    int c8 = (tid & 7) * 8;
    uint4 raw = *(const uint4*)(vb + ((size_t)b * HW + p0 + p) * NC + c0 + c8);
    unsigned int rr[4] = {raw.x, raw.y, raw.z, raw.w};
    for (int i = 0; i < 4; ++i) {
      int c_a = c8 + i * 2, c_b = c8 + i * 2 + 1;
      *(unsigned short*)(tB + ((c_a * 128 + p * 2) ^ SWZ(c_a))) =
          (unsigned short)(rr[i] & 0xffffu);
      *(unsigned short*)(tB + ((c_b * 128 + p * 2) ^ SWZ(c_b))) =
          (unsigned short)(rr[i] >> 16);
    }
  }
  __syncthreads();
  for (int rep = 0; rep < 2; ++rep) {
    int c = (tid >> 3) + rep * 32;
    int p8 = (tid & 7) * 8;
    bf16x8 val = *(const bf16x8*)(tB + ((c * 128 + p8 * 2) ^ SWZ(c)));
    *(bf16x8*)(vT + ((size_t)b * NC + c0 + c) * HW + p0 + p8) = val;
  }
}

// ---------------------------------------------------------------- kernel 4
// Flash attention v2: 4 waves x 32 q-rows = 128 rows/block, 256 blocks
// (1/CU, batch pinned to XCD). K/V double-buffered in LDS, staged via
// global_load_lds with pre-(inverse-)swizzled global source addresses;
// 2-phase pipeline: issue stage(t+1), compute(t), syncthreads (vmcnt drain).
__global__ __launch_bounds__(256, 1) void flash_attn_kernel(
    const unsigned short* __restrict__ qb, const unsigned short* __restrict__ kb,
    const unsigned short* __restrict__ vT, unsigned short* __restrict__ att) {
  int b = blockIdx.x & 7;    // batch -> XCD (round-robin dispatch)
  int qt = blockIdx.x >> 3;  // 0..31, q rows qt*128
  int tid = threadIdx.x;
  int wave = tid >> 6, lane = tid & 63;
  int l15 = lane & 15, q4 = lane >> 4;

  __shared__ unsigned short k_lds[2][64 * 256];  // [j][c] swizzled, 512B rows
  __shared__ unsigned short v_lds[2][256 * 64];  // [c][j] swizzled, 128B rows
  __shared__ unsigned short p_lds[4][32 * 64];   // per-wave P, 128B rows

  const char* kbase = (const char*)(kb + (size_t)b * HW * NC);
  const char* vbase = (const char*)(vT + (size_t)b * NC * HW);

  // Pre-compute inverse-swizzled global source offsets (bytes) so the linear
  // global_load_lds write (dst = base + lane*16) lands the swizzled layout.
  unsigned int ksrc[8], vsrc[8];
#pragma unroll
  for (int i = 0; i < 8; ++i) {
    int dk = wave * 8192 + i * 1024 + lane * 16;
    int j = dk >> 9;
    int t0 = (dk & 511) ^ SWZ(j);
    ksrc[i] = (unsigned)(j * 512 + t0);  // + j0*512 per step
    int dv = wave * 8192 + i * 1024 + lane * 16;
    int cc = dv >> 7;
    int tv = (dv & 127) ^ SWZ(cc);
    vsrc[i] = (unsigned)(cc * 8192 + tv);  // + j0*2 per step
  }

  // Q fragments: 2 row-blocks of 16
  bf16x8 qf[2][8];
#pragma unroll
  for (int rf = 0; rf < 2; ++rf) {
    const unsigned short* qrow =
        qb + ((size_t)b * HW + qt * 128 + wave * 32 + rf * 16 + l15) * NC;
#pragma unroll
    for (int kc = 0; kc < 8; ++kc)
      qf[rf][kc] = *(const bf16x8*)(qrow + kc * 32 + q4 * 8);
  }

  f32x4 acc[2][16];
#pragma unroll
  for (int rf = 0; rf < 2; ++rf)
#pragma unroll
    for (int nb = 0; nb < 16; ++nb) acc[rf][nb] = (f32x4){0.f, 0.f, 0.f, 0.f};
  float m_r[2][4], l_r[2][4];
#pragma unroll
  for (int rf = 0; rf < 2; ++rf)
#pragma unroll
    for (int r = 0; r < 4; ++r) { m_r[rf][r] = -1e30f; l_r[rf][r] = 0.f; }

  char* pB = (char*)p_lds[wave];

  // prologue stage of tile 0
  {
    char* kdst = (char*)k_lds[0] + wave * 8192;
    char* vdst = (char*)v_lds[0] + wave * 8192;
#pragma unroll
    for (int i = 0; i < 8; ++i) gload16(kbase + ksrc[i], kdst + i * 1024);
#pragma unroll
    for (int i = 0; i < 8; ++i) gload16(vbase + vsrc[i], vdst + i * 1024);
  }
  __syncthreads();

  for (int jt = 0; jt < 64; ++jt) {
    int cur = jt & 1;
    if (jt < 63) {  // issue next tile's loads (async, drained at barrier)
      int j0 = (jt + 1) * 64;
      char* kdst = (char*)k_lds[cur ^ 1] + wave * 8192;
      char* vdst = (char*)v_lds[cur ^ 1] + wave * 8192;
#pragma unroll
      for (int i = 0; i < 8; ++i)
        gload16(kbase + ksrc[i] + j0 * 512, kdst + i * 1024);
#pragma unroll
      for (int i = 0; i < 8; ++i)
        gload16(vbase + vsrc[i] + j0 * 2, vdst + i * 1024);
    }
    char* kB = (char*)k_lds[cur];
    char* vB = (char*)v_lds[cur];

    // S = Q K^T : rows (rf*16 + q4*4+r), cols jb*16+l15
    f32x4 sv[2][4];
#pragma unroll
    for (int jb = 0; jb < 4; ++jb) {
      f32x4 a0 = (f32x4){0.f, 0.f, 0.f, 0.f};
      f32x4 a1 = (f32x4){0.f, 0.f, 0.f, 0.f};
      int j = jb * 16 + l15;
#pragma unroll
      for (int kc = 0; kc < 8; ++kc) {
        bf16x8 kf = *(const bf16x8*)(kB + ((j * 512 + kc * 64 + q4 * 16) ^ SWZ(j)));
        a0 = MFMA16(qf[0][kc], kf, a0, 0, 0, 0);
        a1 = MFMA16(qf[1][kc], kf, a1, 0, 0, 0);
      }
      sv[0][jb] = a0;
      sv[1][jb] = a1;
    }

    // online softmax (reduce over cols: 16-lane groups)
    float sf[2][4];
#pragma unroll
    for (int rf = 0; rf < 2; ++rf)
#pragma unroll
      for (int r = 0; r < 4; ++r) {
        float mx = fmaxf(fmaxf(sv[rf][0][r], sv[rf][1][r]),
                         fmaxf(sv[rf][2][r], sv[rf][3][r]));
        mx = fmaxf(mx, __shfl_xor(mx, 1));
        mx = fmaxf(mx, __shfl_xor(mx, 2));
        mx = fmaxf(mx, __shfl_xor(mx, 4));
        mx = fmaxf(mx, __shfl_xor(mx, 8));
        float mn = fmaxf(m_r[rf][r], mx);
        float f = __expf(m_r[rf][r] - mn);
        float rs = 0.f;
#pragma unroll
        for (int jb = 0; jb < 4; ++jb) {
          float p = __expf(sv[rf][jb][r] - mn);
          sv[rf][jb][r] = p;
          rs += p;
        }
        rs += __shfl_xor(rs, 1);
        rs += __shfl_xor(rs, 2);
        rs += __shfl_xor(rs, 4);
        rs += __shfl_xor(rs, 8);
        l_r[rf][r] = l_r[rf][r] * f + rs;
        m_r[rf][r] = mn;
        sf[rf][r] = f;
      }
#pragma unroll
    for (int rf = 0; rf < 2; ++rf)
#pragma unroll
      for (int nb = 0; nb < 16; ++nb) {
        f32x4 t = acc[rf][nb];
        t[0] *= sf[rf][0]; t[1] *= sf[rf][1];
        t[2] *= sf[rf][2]; t[3] *= sf[rf][3];
        acc[rf][nb] = t;
      }

    // P -> per-wave LDS, read back as PV A-fragments
#pragma unroll
    for (int rf = 0; rf < 2; ++rf)
#pragma unroll
      for (int jb = 0; jb < 4; ++jb)
#pragma unroll
        for (int r = 0; r < 4; ++r) {
          int row = rf * 16 + q4 * 4 + r;
          *(unsigned short*)(pB + ((row * 128 + (jb * 16 + l15) * 2) ^ SWZ(row))) =
              f2bf(sv[rf][jb][r]);
        }
    bf16x8 pa[2][2];
#pragma unroll
    for (int rfb = 0; rfb < 2; ++rfb)
#pragma unroll
      for (int kj = 0; kj < 2; ++kj) {
        int row = rfb * 16 + l15;
        pa[rfb][kj] =
            *(const bf16x8*)(pB + ((row * 128 + kj * 64 + q4 * 16) ^ SWZ(row)));
      }

#pragma unroll
    for (int nb = 0; nb < 16; ++nb) {
      int cc = nb * 16 + l15;
#pragma unroll
      for (int kj = 0; kj < 2; ++kj) {
        bf16x8 vf = *(const bf16x8*)(vB + ((cc * 128 + kj * 64 + q4 * 16) ^ SWZ(cc)));
        acc[0][nb] = MFMA16(pa[0][kj], vf, acc[0][nb], 0, 0, 0);
        acc[1][nb] = MFMA16(pa[1][kj], vf, acc[1][nb], 0, 0, 0);
      }
    }
    __syncthreads();  // drains vmcnt (next tile) + protects buf reuse
  }

  float inv[2][4];
#pragma unroll
  for (int rf = 0; rf < 2; ++rf)
#pragma unroll
    for (int r = 0; r < 4; ++r) inv[rf][r] = 1.f / l_r[rf][r];
#pragma unroll
  for (int rf = 0; rf < 2; ++rf)
#pragma unroll
    for (int nb = 0; nb < 16; ++nb)
#pragma unroll
      for (int r = 0; r < 4; ++r) {
        int p = qt * 128 + wave * 32 + rf * 16 + q4 * 4 + r;
        att[((size_t)b * HW + p) * NC + nb * 16 + l15] =
            f2bf(acc[rf][nb][r] * inv[rf][r]);
      }
}

// ---------------------------------------------------------------- kernel 5
__global__ __launch_bounds__(256) void outproj_kernel(
    const float* __restrict__ ow, const float* __restrict__ obias,
    const unsigned short* __restrict__ att, const float* __restrict__ x,
    float* __restrict__ out) {
  int b = blockIdx.y;
  int p0 = blockIdx.x * 64;
  int tid = threadIdx.x;
  int wave = tid >> 6, lane = tid & 63;
  int l15 = lane & 15, q4 = lane >> 4;
  __shared__ unsigned short aw_lds[256 * 64];  // [o][c] swizzled
  __shared__ unsigned short bt_lds[64 * 64];   // [p][c] swizzled
  char* aB = (char*)aw_lds;
  char* bB = (char*)bt_lds;
  f32x4 acc[4][4];
  for (int i = 0; i < 4; ++i)
    for (int j = 0; j < 4; ++j) acc[i][j] = (f32x4){0.f, 0.f, 0.f, 0.f};

  for (int kc0 = 0; kc0 < 256; kc0 += 64) {
    __syncthreads();
    for (int it = 0; it < 16; ++it) {
      int idx = tid + it * 256;
      int o = idx >> 4, c4 = idx & 15;
      float4 wv = *(const float4*)(ow + (size_t)o * NC + kc0 + c4 * 4);
      ushort4 hv = make_ushort4(f2bf(wv.x), f2bf(wv.y), f2bf(wv.z), f2bf(wv.w));
      *(ushort4*)(aB + ((o * 128 + c4 * 8) ^ SWZ(o))) = hv;
    }
    for (int it = 0; it < 2; ++it) {
      int idx = tid + it * 256;
      int p = idx >> 3, c8 = idx & 7;
      uint4 raw = *(const uint4*)(att + ((size_t)b * HW + p0 + p) * NC + kc0 + c8 * 8);
      *(uint4*)(bB + ((p * 128 + c8 * 16) ^ SWZ(p))) = raw;
    }
    __syncthreads();
    for (int kk = 0; kk < 2; ++kk) {
      bf16x8 af[4], bfv[4];
      for (int obk = 0; obk < 4; ++obk) {
        int row = wave * 64 + obk * 16 + l15;
        af[obk] = *(const bf16x8*)(aB + ((row * 128 + kk * 64 + q4 * 16) ^ SWZ(row)));
      }
      for (int pb = 0; pb < 4; ++pb) {
        int row = pb * 16 + l15;
        bfv[pb] = *(const bf16x8*)(bB + ((row * 128 + kk * 64 + q4 * 16) ^ SWZ(row)));
      }
      for (int obk = 0; obk < 4; ++obk)
        for (int pb = 0; pb < 4; ++pb)
          acc[obk][pb] = MFMA16(af[obk], bfv[pb], acc[obk][pb], 0, 0, 0);
    }
  }
  for (int obk = 0; obk < 4; ++obk)
    for (int pb = 0; pb < 4; ++pb)
      for (int r = 0; r < 4; ++r) {
        int o = wave * 64 + obk * 16 + q4 * 4 + r;
        int p = p0 + pb * 16 + l15;
        size_t gi = ((size_t)b * NC + o) * HW + p;
        out[gi] = acc[obk][pb][r] + obias[o] + x[gi];
      }
}

// ---------------------------------------------------------------- launch
extern "C" void kernel_launch(void* const* d_in, const int* in_sizes, int n_in,
                              void* d_out, int out_size, void* d_ws, size_t ws_size,
                              hipStream_t stream) {
  (void)in_sizes; (void)n_in; (void)out_size; (void)ws_size;
  const float* x = (const float*)d_in[0];
  const float* gnw = (const float*)d_in[1];
  const float* gnb = (const float*)d_in[2];
  const float* qkvw = (const float*)d_in[3];
  const float* qkvb = (const float*)d_in[4];
  const float* ow = (const float*)d_in[5];
  const float* obias = (const float*)d_in[6];
  float* out = (float*)d_out;

  char* ws = (char*)d_ws;
  float* s_arr = (float*)ws;
  float* t_arr = s_arr + NB * NC;
  unsigned short* qb = (unsigned short*)(ws + 16384);
  size_t tsz = (size_t)NB * HW * NC;
  unsigned short* kb = qb + tsz;
  unsigned short* vb = kb + tsz;
  unsigned short* vT = vb + tsz;
  unsigned short* att = vT + tsz;

  hipLaunchKernelGGL(gn_stats_kernel, dim3(NB * 32), dim3(256), 0, stream,
                     x, gnw, gnb, s_arr, t_arr);
  hipLaunchKernelGGL(qkv_gemm_kernel, dim3(64, 6, NB), dim3(256), 0, stream,
                     x, s_arr, t_arr, qkvw, qkvb, qb, kb, vb);
  hipLaunchKernelGGL(transpose_v_kernel, dim3(64, 4, NB), dim3(256), 0, stream,
                     vb, vT);
  hipLaunchKernelGGL(flash_attn_kernel, dim3(256), dim3(256), 0, stream,
                     qb, kb, vT, att);
  hipLaunchKernelGGL(outproj_kernel, dim3(64, NB), dim3(256), 0, stream,
                     ow, obias, att, x, out);
}

// Round 3
// 329.096 us; speedup vs baseline: 1.7990x; 1.7099x over previous
//
#include <hip/hip_runtime.h>

#define HW 4096
#define NC 256
#define NB 8
#define GN_EPS 1e-5f

typedef short bf16x8 __attribute__((ext_vector_type(8)));
typedef float f32x4 __attribute__((ext_vector_type(4)));

#define MFMA16 __builtin_amdgcn_mfma_f32_16x16x32_bf16

// XOR swizzle key: distinct 16B-slot for 8 consecutive rows, mixed with row>>3
// so stride-4 / stride-8 writers also spread. Window = 128 B.
#define SWZ(row) ((((row) & 7) ^ (((row) >> 3) & 7)) << 4)

// q-scale folds 1/sqrt(256) AND log2(e) so softmax runs in base-2.
#define QSCALE 0.09016844f

__device__ __forceinline__ unsigned short f2bf(float f) {
  unsigned int u = __float_as_uint(f);
  u = (u + 0x7FFFu + ((u >> 16) & 1u)) >> 16;
  return (unsigned short)u;
}

// async global->LDS, 16B per lane. LDS dst must be wave-uniform; HW adds lane*16.
__device__ __forceinline__ void gload16(const void* g, void* l) {
  __builtin_amdgcn_global_load_lds(
      (const __attribute__((address_space(1))) void*)g,
      (__attribute__((address_space(3))) void*)l, 16, 0, 0);
}

// ---------------------------------------------------------------- kernel 1
__global__ void gn_stats_kernel(const float* __restrict__ x,
                                const float* __restrict__ gnw,
                                const float* __restrict__ gnb,
                                float* __restrict__ s_arr,
                                float* __restrict__ t_arr) {
  int bg = blockIdx.x;
  int b = bg >> 5, g = bg & 31;
  const float4* base = (const float4*)(x + ((size_t)b * NC + g * 8) * HW);
  int tid = threadIdx.x;
  float s = 0.f, ss = 0.f;
  for (int it = 0; it < 32; ++it) {
    float4 v = base[tid + it * 256];
    s += v.x + v.y + v.z + v.w;
    ss += v.x * v.x + v.y * v.y + v.z * v.z + v.w * v.w;
  }
  for (int off = 32; off; off >>= 1) {
    s += __shfl_down(s, off);
    ss += __shfl_down(ss, off);
  }
  __shared__ float red[8];
  __shared__ float bc[2];
  int wave = tid >> 6, lane = tid & 63;
  if (lane == 0) { red[wave] = s; red[4 + wave] = ss; }
  __syncthreads();
  if (tid == 0) {
    float S = red[0] + red[1] + red[2] + red[3];
    float SS = red[4] + red[5] + red[6] + red[7];
    float mean = S * (1.f / 32768.f);
    float var = SS * (1.f / 32768.f) - mean * mean;
    bc[0] = mean;
    bc[1] = rsqrtf(var + GN_EPS);
  }
  __syncthreads();
  if (tid < 8) {
    int c = g * 8 + tid;
    float sv = bc[1] * gnw[c];
    s_arr[b * NC + c] = sv;
    t_arr[b * NC + c] = gnb[c] - bc[0] * sv;
  }
}

// ---------------------------------------------------------------- kernel 2
__global__ __launch_bounds__(256) void qkv_gemm_kernel(
    const float* __restrict__ x, const float* __restrict__ s_arr,
    const float* __restrict__ t_arr, const float* __restrict__ w,
    const float* __restrict__ bias, unsigned short* __restrict__ qb,
    unsigned short* __restrict__ kb, unsigned short* __restrict__ vb) {
  int b = blockIdx.z;
  int p0 = blockIdx.x * 64;
  int o0 = blockIdx.y * 128;
  int tid = threadIdx.x;
  int wave = tid >> 6, lane = tid & 63;
  int l15 = lane & 15, q4 = lane >> 4;
  int wm = wave >> 1, wn = wave & 1;
  __shared__ unsigned short a_lds[64 * 64];   // [p][c] swizzled
  __shared__ unsigned short b_lds[128 * 64];  // [o][c] swizzled
  char* aB = (char*)a_lds;
  char* bB = (char*)b_lds;
  f32x4 acc[2][4];
  for (int i = 0; i < 2; ++i)
    for (int j = 0; j < 4; ++j) acc[i][j] = (f32x4){0.f, 0.f, 0.f, 0.f};

  for (int kc0 = 0; kc0 < 256; kc0 += 64) {
    __syncthreads();
    for (int it = 0; it < 4; ++it) {
      int idx = tid + it * 256;
      int c = idx >> 4, p4 = idx & 15;
      float4 xv = *(const float4*)(x + ((size_t)b * NC + kc0 + c) * HW + p0 + p4 * 4);
      float sc = s_arr[b * NC + kc0 + c];
      float tc = t_arr[b * NC + kc0 + c];
      float vals[4] = {xv.x, xv.y, xv.z, xv.w};
      for (int i = 0; i < 4; ++i) {
        int p = p4 * 4 + i;
        *(unsigned short*)(aB + ((p * 128 + c * 2) ^ SWZ(p))) =
            f2bf(vals[i] * sc + tc);
      }
    }
    for (int it = 0; it < 8; ++it) {
      int idx = tid + it * 256;
      int o = idx >> 4, c4 = idx & 15;
      float4 wv = *(const float4*)(w + (size_t)(o0 + o) * NC + kc0 + c4 * 4);
      ushort4 hv = make_ushort4(f2bf(wv.x), f2bf(wv.y), f2bf(wv.z), f2bf(wv.w));
      *(ushort4*)(bB + ((o * 128 + c4 * 8) ^ SWZ(o))) = hv;
    }
    __syncthreads();
    for (int kk = 0; kk < 2; ++kk) {
      bf16x8 af[2], bfv[4];
      for (int pb = 0; pb < 2; ++pb) {
        int row = wm * 32 + pb * 16 + l15;
        af[pb] = *(const bf16x8*)(aB + ((row * 128 + kk * 64 + q4 * 16) ^ SWZ(row)));
      }
      for (int ob = 0; ob < 4; ++ob) {
        int row = wn * 64 + ob * 16 + l15;
        bfv[ob] = *(const bf16x8*)(bB + ((row * 128 + kk * 64 + q4 * 16) ^ SWZ(row)));
      }
      for (int pb = 0; pb < 2; ++pb)
        for (int ob = 0; ob < 4; ++ob)
          acc[pb][ob] = MFMA16(af[pb], bfv[ob], acc[pb][ob], 0, 0, 0);
    }
  }
  for (int pb = 0; pb < 2; ++pb) {
    for (int ob = 0; ob < 4; ++ob) {
      int og = o0 + wn * 64 + ob * 16 + l15;
      int tsel = og >> 8, oc = og & 255;
      unsigned short* dst = tsel == 0 ? qb : (tsel == 1 ? kb : vb);
      float bi = bias[og];
      float qscale = (tsel == 0) ? QSCALE : 1.0f;
      for (int r = 0; r < 4; ++r) {
        int p = p0 + wm * 32 + pb * 16 + q4 * 4 + r;
        dst[((size_t)b * HW + p) * NC + oc] = f2bf((acc[pb][ob][r] + bi) * qscale);
      }
    }
  }
}

// ---------------------------------------------------------------- kernel 3
__global__ void transpose_v_kernel(const unsigned short* __restrict__ vb,
                                   unsigned short* __restrict__ vT) {
  int b = blockIdx.z;
  int p0 = blockIdx.x * 64, c0 = blockIdx.y * 64;
  int tid = threadIdx.x;
  __shared__ unsigned short tl[64 * 64];  // [c][p] swizzled
  char* tB = (char*)tl;
  for (int rep = 0; rep < 2; ++rep) {
    int p = (tid >> 3) + rep * 32;
    int c8 = (tid & 7) * 8;
    uint4 raw = *(const uint4*)(vb + ((size_t)b * HW + p0 + p) * NC + c0 + c8);
    unsigned int rr[4] = {raw.x, raw.y, raw.z, raw.w};
    for (int i = 0; i < 4; ++i) {
      int c_a = c8 + i * 2, c_b = c8 + i * 2 + 1;
      *(unsigned short*)(tB + ((c_a * 128 + p * 2) ^ SWZ(c_a))) =
          (unsigned short)(rr[i] & 0xffffu);
      *(unsigned short*)(tB + ((c_b * 128 + p * 2) ^ SWZ(c_b))) =
          (unsigned short)(rr[i] >> 16);
    }
  }
  __syncthreads();
  for (int rep = 0; rep < 2; ++rep) {
    int c = (tid >> 3) + rep * 32;
    int p8 = (tid & 7) * 8;
    bf16x8 val = *(const bf16x8*)(tB + ((c * 128 + p8 * 2) ^ SWZ(c)));
    *(bf16x8*)(vT + ((size_t)b * NC + c0 + c) * HW + p0 + p8) = val;
  }
}

// ---------------------------------------------------------------- kernel 4
// Flash attention v3: 8 waves x 16 q-rows = 128 rows/block, 256 blocks
// (1 block/CU, 2 waves/SIMD). K/V double-buffered via global_load_lds with
// pre-inverse-swizzled global sources. Base-2 online softmax with defer-max
// (THR=12 in log2 units): rescale of acc/l skipped unless the running max
// actually grows, P bounded by 2^12 (safe in bf16/f32).
__global__ __launch_bounds__(512, 2) void flash_attn_kernel(
    const unsigned short* __restrict__ qb, const unsigned short* __restrict__ kb,
    const unsigned short* __restrict__ vT, unsigned short* __restrict__ att) {
  int b = blockIdx.x & 7;    // batch -> XCD (round-robin dispatch)
  int qt = blockIdx.x >> 3;  // 0..31, q rows qt*128
  int tid = threadIdx.x;
  int wave = tid >> 6, lane = tid & 63;
  int l15 = lane & 15, q4 = lane >> 4;

  __shared__ unsigned short k_lds[2][64 * 256];  // [j][c] swizzled, 512B rows
  __shared__ unsigned short v_lds[2][256 * 64];  // [c][j] swizzled, 128B rows
  __shared__ unsigned short p_lds[8][16 * 64];   // per-wave P, 128B rows

  const char* kbase = (const char*)(kb + (size_t)b * HW * NC);
  const char* vbase = (const char*)(vT + (size_t)b * NC * HW);

  // inverse-swizzled global byte offsets; each wave stages 4KB of K + 4KB of V
  unsigned int ksrc[4], vsrc[4];
#pragma unroll
  for (int i = 0; i < 4; ++i) {
    int dk = wave * 4096 + i * 1024 + lane * 16;
    int j = dk >> 9;
    int t0 = (dk & 511) ^ SWZ(j);
    ksrc[i] = (unsigned)(j * 512 + t0);  // + j0*512 per step
    int cc = dk >> 7;
    int tv = (dk & 127) ^ SWZ(cc);
    vsrc[i] = (unsigned)(cc * 8192 + tv);  // + j0*2 per step
  }

  bf16x8 qf[8];
  const unsigned short* qrow =
      qb + ((size_t)b * HW + qt * 128 + wave * 16 + l15) * NC;
#pragma unroll
  for (int kc = 0; kc < 8; ++kc)
    qf[kc] = *(const bf16x8*)(qrow + kc * 32 + q4 * 8);

  f32x4 acc[16];
#pragma unroll
  for (int i = 0; i < 16; ++i) acc[i] = (f32x4){0.f, 0.f, 0.f, 0.f};
  float m_r[4] = {-1e30f, -1e30f, -1e30f, -1e30f};
  float l_r[4] = {0.f, 0.f, 0.f, 0.f};

  char* pB = (char*)p_lds[wave];

  {  // prologue stage of tile 0
    char* kdst = (char*)k_lds[0] + wave * 4096;
    char* vdst = (char*)v_lds[0] + wave * 4096;
#pragma unroll
    for (int i = 0; i < 4; ++i) gload16(kbase + ksrc[i], kdst + i * 1024);
#pragma unroll
    for (int i = 0; i < 4; ++i) gload16(vbase + vsrc[i], vdst + i * 1024);
  }
  __syncthreads();

  for (int jt = 0; jt < 64; ++jt) {
    int cur = jt & 1;
    if (jt < 63) {  // issue next tile's loads (drained at the end barrier)
      int j0 = (jt + 1) * 64;
      char* kdst = (char*)k_lds[cur ^ 1] + wave * 4096;
      char* vdst = (char*)v_lds[cur ^ 1] + wave * 4096;
#pragma unroll
      for (int i = 0; i < 4; ++i)
        gload16(kbase + ksrc[i] + j0 * 512, kdst + i * 1024);
#pragma unroll
      for (int i = 0; i < 4; ++i)
        gload16(vbase + vsrc[i] + j0 * 2, vdst + i * 1024);
    }
    char* kB = (char*)k_lds[cur];
    char* vB = (char*)v_lds[cur];

    // S = Q K^T : rows q4*4+r, cols jb*16+l15 (S already includes log2e)
    f32x4 sv[4];
    __builtin_amdgcn_s_setprio(1);
#pragma unroll
    for (int jb = 0; jb < 4; ++jb) {
      f32x4 a = (f32x4){0.f, 0.f, 0.f, 0.f};
      int j = jb * 16 + l15;
#pragma unroll
      for (int kc = 0; kc < 8; ++kc) {
        bf16x8 kf = *(const bf16x8*)(kB + ((j * 512 + kc * 64 + q4 * 16) ^ SWZ(j)));
        a = MFMA16(qf[kc], kf, a, 0, 0, 0);
      }
      sv[jb] = a;
    }
    __builtin_amdgcn_s_setprio(0);

    // base-2 online softmax with defer-max
    float pmax[4];
#pragma unroll
    for (int r = 0; r < 4; ++r) {
      float mx = fmaxf(fmaxf(sv[0][r], sv[1][r]), fmaxf(sv[2][r], sv[3][r]));
      mx = fmaxf(mx, __shfl_xor(mx, 1));
      mx = fmaxf(mx, __shfl_xor(mx, 2));
      mx = fmaxf(mx, __shfl_xor(mx, 4));
      mx = fmaxf(mx, __shfl_xor(mx, 8));
      pmax[r] = mx;
    }
    float worst = fmaxf(fmaxf(pmax[0] - m_r[0], pmax[1] - m_r[1]),
                        fmaxf(pmax[2] - m_r[2], pmax[3] - m_r[3]));
    if (!__all(worst <= 12.0f)) {  // rare: running max grew, rescale
      float sf[4];
#pragma unroll
      for (int r = 0; r < 4; ++r) {
        float mn = fmaxf(m_r[r], pmax[r]);
        sf[r] = exp2f(m_r[r] - mn);
        m_r[r] = mn;
        l_r[r] *= sf[r];
      }
#pragma unroll
      for (int nb = 0; nb < 16; ++nb) {
        f32x4 t = acc[nb];
        t[0] *= sf[0]; t[1] *= sf[1]; t[2] *= sf[2]; t[3] *= sf[3];
        acc[nb] = t;
      }
    }
#pragma unroll
    for (int r = 0; r < 4; ++r) {
      float rs = 0.f;
#pragma unroll
      for (int jb = 0; jb < 4; ++jb) {
        float p = exp2f(sv[jb][r] - m_r[r]);
        sv[jb][r] = p;
        rs += p;
      }
      rs += __shfl_xor(rs, 1);
      rs += __shfl_xor(rs, 2);
      rs += __shfl_xor(rs, 4);
      rs += __shfl_xor(rs, 8);
      l_r[r] += rs;
    }

    // P -> per-wave LDS, read back as PV A-fragments
#pragma unroll
    for (int jb = 0; jb < 4; ++jb)
#pragma unroll
      for (int r = 0; r < 4; ++r) {
        int row = q4 * 4 + r;
        *(unsigned short*)(pB + ((row * 128 + (jb * 16 + l15) * 2) ^ SWZ(row))) =
            f2bf(sv[jb][r]);
      }
    bf16x8 pa[2];
#pragma unroll
    for (int kj = 0; kj < 2; ++kj)
      pa[kj] = *(const bf16x8*)(pB + ((l15 * 128 + kj * 64 + q4 * 16) ^ SWZ(l15)));

    __builtin_amdgcn_s_setprio(1);
#pragma unroll
    for (int nb = 0; nb < 16; ++nb) {
      int cc = nb * 16 + l15;
#pragma unroll
      for (int kj = 0; kj < 2; ++kj) {
        bf16x8 vf = *(const bf16x8*)(vB + ((cc * 128 + kj * 64 + q4 * 16) ^ SWZ(cc)));
        acc[nb] = MFMA16(pa[kj], vf, acc[nb], 0, 0, 0);
      }
    }
    __builtin_amdgcn_s_setprio(0);
    __syncthreads();  // drains vmcnt (next tile) + protects buf reuse
  }

  float inv[4];
#pragma unroll
  for (int r = 0; r < 4; ++r) inv[r] = 1.f / l_r[r];
#pragma unroll
  for (int nb = 0; nb < 16; ++nb)
#pragma unroll
    for (int r = 0; r < 4; ++r) {
      int p = qt * 128 + wave * 16 + q4 * 4 + r;
      att[((size_t)b * HW + p) * NC + nb * 16 + l15] = f2bf(acc[nb][r] * inv[r]);
    }
}

// ---------------------------------------------------------------- kernel 5
__global__ __launch_bounds__(256) void outproj_kernel(
    const float* __restrict__ ow, const float* __restrict__ obias,
    const unsigned short* __restrict__ att, const float* __restrict__ x,
    float* __restrict__ out) {
  int b = blockIdx.y;
  int p0 = blockIdx.x * 64;
  int tid = threadIdx.x;
  int wave = tid >> 6, lane = tid & 63;
  int l15 = lane & 15, q4 = lane >> 4;
  __shared__ unsigned short aw_lds[256 * 64];  // [o][c] swizzled
  __shared__ unsigned short bt_lds[64 * 64];   // [p][c] swizzled
  char* aB = (char*)aw_lds;
  char* bB = (char*)bt_lds;
  f32x4 acc[4][4];
  for (int i = 0; i < 4; ++i)
    for (int j = 0; j < 4; ++j) acc[i][j] = (f32x4){0.f, 0.f, 0.f, 0.f};

  for (int kc0 = 0; kc0 < 256; kc0 += 64) {
    __syncthreads();
    for (int it = 0; it < 16; ++it) {
      int idx = tid + it * 256;
      int o = idx >> 4, c4 = idx & 15;
      float4 wv = *(const float4*)(ow + (size_t)o * NC + kc0 + c4 * 4);
      ushort4 hv = make_ushort4(f2bf(wv.x), f2bf(wv.y), f2bf(wv.z), f2bf(wv.w));
      *(ushort4*)(aB + ((o * 128 + c4 * 8) ^ SWZ(o))) = hv;
    }
    for (int it = 0; it < 2; ++it) {
      int idx = tid + it * 256;
      int p = idx >> 3, c8 = idx & 7;
      uint4 raw = *(const uint4*)(att + ((size_t)b * HW + p0 + p) * NC + kc0 + c8 * 8);
      *(uint4*)(bB + ((p * 128 + c8 * 16) ^ SWZ(p))) = raw;
    }
    __syncthreads();
    for (int kk = 0; kk < 2; ++kk) {
      bf16x8 af[4], bfv[4];
      for (int obk = 0; obk < 4; ++obk) {
        int row = wave * 64 + obk * 16 + l15;
        af[obk] = *(const bf16x8*)(aB + ((row * 128 + kk * 64 + q4 * 16) ^ SWZ(row)));
      }
      for (int pb = 0; pb < 4; ++pb) {
        int row = pb * 16 + l15;
        bfv[pb] = *(const bf16x8*)(bB + ((row * 128 + kk * 64 + q4 * 16) ^ SWZ(row)));
      }
      for (int obk = 0; obk < 4; ++obk)
        for (int pb = 0; pb < 4; ++pb)
          acc[obk][pb] = MFMA16(af[obk], bfv[pb], acc[obk][pb], 0, 0, 0);
    }
  }
  for (int obk = 0; obk < 4; ++obk)
    for (int pb = 0; pb < 4; ++pb)
      for (int r = 0; r < 4; ++r) {
        int o = wave * 64 + obk * 16 + q4 * 4 + r;
        int p = p0 + pb * 16 + l15;
        size_t gi = ((size_t)b * NC + o) * HW + p;
        out[gi] = acc[obk][pb][r] + obias[o] + x[gi];
      }
}

// ---------------------------------------------------------------- launch
extern "C" void kernel_launch(void* const* d_in, const int* in_sizes, int n_in,
                              void* d_out, int out_size, void* d_ws, size_t ws_size,
                              hipStream_t stream) {
  (void)in_sizes; (void)n_in; (void)out_size; (void)ws_size;
  const float* x = (const float*)d_in[0];
  const float* gnw = (const float*)d_in[1];
  const float* gnb = (const float*)d_in[2];
  const float* qkvw = (const float*)d_in[3];
  const float* qkvb = (const float*)d_in[4];
  const float* ow = (const float*)d_in[5];
  const float* obias = (const float*)d_in[6];
  float* out = (float*)d_out;

  char* ws = (char*)d_ws;
  float* s_arr = (float*)ws;
  float* t_arr = s_arr + NB * NC;
  unsigned short* qb = (unsigned short*)(ws + 16384);
  size_t tsz = (size_t)NB * HW * NC;
  unsigned short* kb = qb + tsz;
  unsigned short* vb = kb + tsz;
  unsigned short* vT = vb + tsz;
  unsigned short* att = vT + tsz;

  hipLaunchKernelGGL(gn_stats_kernel, dim3(NB * 32), dim3(256), 0, stream,
                     x, gnw, gnb, s_arr, t_arr);
  hipLaunchKernelGGL(qkv_gemm_kernel, dim3(64, 6, NB), dim3(256), 0, stream,
                     x, s_arr, t_arr, qkvw, qkvb, qb, kb, vb);
  hipLaunchKernelGGL(transpose_v_kernel, dim3(64, 4, NB), dim3(256), 0, stream,
                     vb, vT);
  hipLaunchKernelGGL(flash_attn_kernel, dim3(256), dim3(512), 0, stream,
                     qb, kb, vT, att);
  hipLaunchKernelGGL(outproj_kernel, dim3(64, NB), dim3(256), 0, stream,
                     ow, obias, att, x, out);
}